// Round 7
// baseline (227.354 us; speedup 1.0000x reference)
//
#include <hip/hip_runtime.h>
#include <hip/hip_bf16.h>

#define EMB 10
#define DIN 36    // 2*EMB + 16 numeric
#define HID 128
#define BM  128   // rows per tile
#define GRID 1024 // persistent blocks (~4/CU resident)

typedef __attribute__((ext_vector_type(8))) short short8;   // bf16x8 MFMA frag
typedef __attribute__((ext_vector_type(4))) float f32x4;    // fp32x4 acc frag

union U8 { unsigned u[4]; short8 v; };

__device__ __forceinline__ short bf16_hi(float v) {
  __hip_bfloat16 h = __float2bfloat16(v);
  return *reinterpret_cast<short*>(&h);
}
__device__ __forceinline__ float bf16_to_f(short s) {
  __hip_bfloat16 h = *reinterpret_cast<__hip_bfloat16*>(&s);
  return __bfloat162float(h);
}

// Truncation hi/lo split for a PAIR of floats, packed via v_perm_b32.
__device__ __forceinline__ void split_pair(float a, float b, unsigned &hi, unsigned &lo) {
  unsigned ua = __float_as_uint(a), ub = __float_as_uint(b);
  hi = __builtin_amdgcn_perm(ub, ua, 0x07060302u);   // [hi16(b) : hi16(a)]
  float ra = a - __uint_as_float(ua & 0xFFFF0000u);
  float rb = b - __uint_as_float(ub & 0xFFFF0000u);
  lo = __builtin_amdgcn_perm(__float_as_uint(rb), __float_as_uint(ra), 0x07060302u);
}

// Pack W1 (36x128) + b1 (k=36 bias row) into hi/lo bf16 B-fragments, K padded 64.
// Layout: [term(2)][ct(8)][ks(2)][lane(64)][e(8)] bf16.
__global__ void prep_kernel(const float* __restrict__ W1, const float* __restrict__ b1,
                            short* __restrict__ Bpack) {
  int b = blockIdx.x;          // 32 blocks
  int term = b >> 4;
  int ct   = (b >> 1) & 7;
  int ks   = b & 1;
  int l = threadIdx.x;         // 0..63
  int col = ct * 16 + (l & 15);
  int kb  = ks * 32 + (l >> 4) * 8;
  short8 o;
#pragma unroll
  for (int e = 0; e < 8; ++e) {
    int k = kb + e;
    float v = 0.0f;
    if (k < DIN)       v = W1[k * HID + col];
    else if (k == DIN) v = b1[col];
    short hb = bf16_hi(v);
    o[e] = (term == 0) ? hb : bf16_hi(v - bf16_to_f(hb));
  }
  *(short8*)(Bpack + (size_t)(((term * 8 + ct) * 2 + ks) * 64 + l) * 8) = o;
}

// Persistent pipelined kernel: each block owns a contiguous tile range;
// tile t+1's idx/gather/numeric loads fly under tile t's build+MFMA.
__global__ __launch_bounds__(256)
void fused_kernel(const int* __restrict__ t1, const int* __restrict__ t2,
                  const float* __restrict__ numf,
                  const float* __restrict__ tab1, const float* __restrict__ tab2,
                  const short* __restrict__ Bpack,
                  const float* __restrict__ W2, const float* __restrict__ b2,
                  float* __restrict__ out, int N, int ntiles) {
  __shared__ float E1[134][11];     // 130 halo rows + 4 pad (clamp-free strips)
  __shared__ float E2[136][11];     // 134 halo rows + 2 pad
  __shared__ float Cs[BM][38];      // combined rows: [36]=1 bias, [37]=0 pad
  __shared__ float W2s[HID];

  const int tid = threadIdx.x;
  const int wid = tid >> 6, l = tid & 63;
  const int arow = l & 15, kg = l >> 4;
  const int rloc = tid & 127, half = tid >> 7;
  const int h2 = tid - 122;          // E2 halo row (>=0 for tid>=122)

  // contiguous tile chunk for this block
  const int G = GRID, bb_ = blockIdx.x;
  const int q = ntiles / G, r = ntiles % G;
  long tbeg, tend;
  if (bb_ < r) { tbeg = (long)bb_ * (q + 1); tend = tbeg + q + 1; }
  else         { tbeg = (long)r * (q + 1) + (long)(bb_ - r) * q; tend = tbeg + q; }

  if (tid < HID) W2s[tid] = W2[tid];
  const float b2v = b2[0];

  // ---- prologue: prefetch tile tbeg into registers ----
  long base = tbeg * BM;
  float2 r1[5], r2[5];
  float4 nfa = make_float4(0,0,0,0), nfb = make_float4(0,0,0,0);
  {
    int i1 = -1, i2 = -1;
    if (tid < 130) { long g = base - 1 + tid; if (g >= 0 && g < (long)N) i1 = t1[g]; }
    if (h2 >= 0)   { long g = base - 3 + h2;  if (g >= 0 && g < (long)N) i2 = t2[g]; }
    if (i1 >= 0) {
      const float2* s = (const float2*)(tab1 + (long)i1 * EMB);
#pragma unroll
      for (int i = 0; i < 5; ++i) r1[i] = s[i];
    } else {
#pragma unroll
      for (int i = 0; i < 5; ++i) r1[i] = make_float2(0.f, 0.f);
    }
    if (i2 >= 0) {
      const float2* s = (const float2*)(tab2 + (long)i2 * EMB);
#pragma unroll
      for (int i = 0; i < 5; ++i) r2[i] = s[i];
    } else {
#pragma unroll
      for (int i = 0; i < 5; ++i) r2[i] = make_float2(0.f, 0.f);
    }
    long rowm = base + rloc;
    if (rowm < (long)N) {
      const float4* np = (const float4*)(numf + rowm * 16 + half * 8);
      nfa = np[0]; nfb = np[1];
    }
  }

  for (long t = tbeg; t < tend; ++t) {
    base = t * BM;
    const long basen = base + BM;
    const bool hasnext = (t + 1 < tend);

    // ---- step1: LDS-write current tile's gathered rows ----
    if (tid < 130) {
#pragma unroll
      for (int i = 0; i < 5; ++i) { E1[tid][2*i] = r1[i].x; E1[tid][2*i+1] = r1[i].y; }
    }
    if (h2 >= 0) {
#pragma unroll
      for (int i = 0; i < 5; ++i) { E2[h2][2*i] = r2[i].x; E2[h2][2*i+1] = r2[i].y; }
    }
    __syncthreads();   // A: E1/E2 ready; also fences prev tile's Cs reads

    // ---- step2: prefetch next tile's indices (latency hidden by build) ----
    int i1n = -1, i2n = -1;
    if (hasnext) {
      if (tid < 130) { long g = basen - 1 + tid; if (g >= 0 && g < (long)N) i1n = t1[g]; }
      if (h2 >= 0)   { long g = basen - 3 + h2;  if (g >= 0 && g < (long)N) i2n = t2[g]; }
    }

    // ---- step3: BUILD (sliding windows -> Cs[0..19]; numeric -> Cs[20..35]) ----
    const bool edgeblk = (base == 0) || (base + BM + 3 > (long)N);
    if (tid < 120) {
      int grp = tid / 10, d = tid - grp * 10;
      int r0 = grp * 11;
      float e[13];
#pragma unroll
      for (int i = 0; i < 13; ++i) e[i] = E1[r0 + i][d];
      if (!edgeblk) {
#pragma unroll
        for (int i = 0; i < 11; ++i) {
          int rr = r0 + i;
          if (rr < BM) Cs[rr][d] = (e[i] + e[i + 1] + e[i + 2]) * (1.0f / 3.0f);
        }
      } else {
#pragma unroll
        for (int i = 0; i < 11; ++i) {
          int rr = r0 + i;
          if (rr < BM) {
            long row = base + rr;
            long lo = row - 1; if (lo < 0) lo = 0;
            long hi = row + 2; if (hi > (long)N) hi = (long)N;
            long c = hi - lo;  if (c < 1) c = 1;
            Cs[rr][d] = (e[i] + e[i + 1] + e[i + 2]) / (float)c;
          }
        }
      }
    } else if (tid < 250) {
      int u = tid - 120;
      int grp = u / 10, d = u - grp * 10;
      int r0 = grp * 10;
      float e[16];
#pragma unroll
      for (int i = 0; i < 16; ++i) e[i] = E2[r0 + i][d];
      float w = e[0] + e[1] + e[2] + e[3] + e[4] + e[5] + e[6];
      if (!edgeblk) {
#pragma unroll
        for (int i = 0; i < 10; ++i) {
          int rr = r0 + i;
          if (rr < BM) Cs[rr][10 + d] = w * (1.0f / 7.0f);
          if (i < 9) w += e[i + 7] - e[i];
        }
      } else {
#pragma unroll
        for (int i = 0; i < 10; ++i) {
          int rr = r0 + i;
          if (rr < BM) {
            long row = base + rr;
            long lo = row - 3; if (lo < 0) lo = 0;
            long hi = row + 4; if (hi > (long)N) hi = (long)N;
            long c = hi - lo;  if (c < 1) c = 1;
            Cs[rr][10 + d] = w / (float)c;
          }
          if (i < 9) w += e[i + 7] - e[i];
        }
      }
    }
    {
      long rowm = base + rloc;
      if (rowm < (long)N) {
        float* cp = &Cs[rloc][20 + half * 8];
        cp[0] = nfa.x; cp[1] = nfa.y; cp[2] = nfa.z; cp[3] = nfa.w;
        cp[4] = nfb.x; cp[5] = nfb.y; cp[6] = nfb.z; cp[7] = nfb.w;
      }
      if (half == 0) { Cs[rloc][36] = 1.0f; Cs[rloc][37] = 0.0f; }
    }
    __syncthreads();   // B: Cs ready

    // ---- step4: prefetch next tile's rows + numeric (flies under MFMA) ----
    if (hasnext) {
      if (tid < 130) {
        if (i1n >= 0) {
          const float2* s = (const float2*)(tab1 + (long)i1n * EMB);
#pragma unroll
          for (int i = 0; i < 5; ++i) r1[i] = s[i];
        } else {
#pragma unroll
          for (int i = 0; i < 5; ++i) r1[i] = make_float2(0.f, 0.f);
        }
      }
      if (h2 >= 0) {
        if (i2n >= 0) {
          const float2* s = (const float2*)(tab2 + (long)i2n * EMB);
#pragma unroll
          for (int i = 0; i < 5; ++i) r2[i] = s[i];
        } else {
#pragma unroll
          for (int i = 0; i < 5; ++i) r2[i] = make_float2(0.f, 0.f);
        }
      }
      long rowm = basen + rloc;
      if (rowm < (long)N) {
        const float4* np = (const float4*)(numf + rowm * 16 + half * 8);
        nfa = np[0]; nfb = np[1];
      } else { nfa = make_float4(0,0,0,0); nfb = make_float4(0,0,0,0); }
    }

    // ---- step5: MFMA + epilogue for tile t ----
    // A frag (16x16x32): row = lane&15, k = ks*32 + kg*8 + e.
    short8 aHi[2][2], aLo[2][2];
#pragma unroll
    for (int rtl = 0; rtl < 2; ++rtl) {
      const int rr = (wid * 2 + rtl) * 16 + arow;
      const float* crow = &Cs[rr][0];
      U8 h0, l0, h1, l1;
#pragma unroll
      for (int i = 0; i < 4; ++i) {
        float2 tt = *(const float2*)(crow + kg * 8 + 2 * i);
        split_pair(tt.x, tt.y, h0.u[i], l0.u[i]);
      }
      if (kg == 0) {     // ks1: k32-35 numeric n12-15, k36 bias, k37+ zero
        float2 t0 = *(const float2*)(crow + 32);
        float2 t1v = *(const float2*)(crow + 34);
        float2 t2v = *(const float2*)(crow + 36);    // (1.0, 0.0)
        split_pair(t0.x, t0.y, h1.u[0], l1.u[0]);
        split_pair(t1v.x, t1v.y, h1.u[1], l1.u[1]);
        split_pair(t2v.x, t2v.y, h1.u[2], l1.u[2]);
        h1.u[3] = 0u; l1.u[3] = 0u;
      } else {
        h1.u[0] = h1.u[1] = h1.u[2] = h1.u[3] = 0u;
        l1.u[0] = l1.u[1] = l1.u[2] = l1.u[3] = 0u;
      }
      aHi[rtl][0] = h0.v; aLo[rtl][0] = l0.v;
      aHi[rtl][1] = h1.v; aLo[rtl][1] = l1.v;
    }

    float part[2][4] = {{0,0,0,0},{0,0,0,0}};
#pragma unroll
    for (int ct = 0; ct < 8; ++ct) {
      short8 bh0 = *(const short8*)(Bpack + (size_t)(((0*8 + ct)*2 + 0)*64 + l)*8);
      short8 bh1 = *(const short8*)(Bpack + (size_t)(((0*8 + ct)*2 + 1)*64 + l)*8);
      short8 bl0 = *(const short8*)(Bpack + (size_t)(((1*8 + ct)*2 + 0)*64 + l)*8);
      short8 bl1 = *(const short8*)(Bpack + (size_t)(((1*8 + ct)*2 + 1)*64 + l)*8);
      float w2c = W2s[ct * 16 + (l & 15)];
#pragma unroll
      for (int rtl = 0; rtl < 2; ++rtl) {
        f32x4 acc = {0.0f, 0.0f, 0.0f, 0.0f};
        acc = __builtin_amdgcn_mfma_f32_16x16x32_bf16(aHi[rtl][0], bh0, acc, 0, 0, 0);
        acc = __builtin_amdgcn_mfma_f32_16x16x32_bf16(aLo[rtl][0], bh0, acc, 0, 0, 0);
        acc = __builtin_amdgcn_mfma_f32_16x16x32_bf16(aHi[rtl][0], bl0, acc, 0, 0, 0);
        acc = __builtin_amdgcn_mfma_f32_16x16x32_bf16(aHi[rtl][1], bh1, acc, 0, 0, 0);
        acc = __builtin_amdgcn_mfma_f32_16x16x32_bf16(aLo[rtl][1], bh1, acc, 0, 0, 0);
        acc = __builtin_amdgcn_mfma_f32_16x16x32_bf16(aHi[rtl][1], bl1, acc, 0, 0, 0);
#pragma unroll
        for (int rg = 0; rg < 4; ++rg) {
          float hv = fmaxf(acc[rg], 0.0f);
          part[rtl][rg] += hv * w2c;
        }
      }
    }
#pragma unroll
    for (int off = 1; off < 16; off <<= 1) {
#pragma unroll
      for (int rtl = 0; rtl < 2; ++rtl)
#pragma unroll
        for (int rg = 0; rg < 4; ++rg)
          part[rtl][rg] += __shfl_xor(part[rtl][rg], off, 64);
    }
    if ((l & 15) < 4) {
#pragma unroll
      for (int rtl = 0; rtl < 2; ++rtl) {
        int rt = wid * 2 + rtl;
        long grow = base + rt * 16 + (l >> 4) * 4 + (l & 15);
        if (grow < (long)N) {
          float x = part[rtl][l & 15] + b2v;
          out[grow] = 1.0f / (1.0f + exp2f(x * -1.44269504f));
        }
      }
    }
    // no barrier here: syncA of the next iteration fences Cs reuse (E1/E2
    // writes at step1 don't conflict with step5's Cs/W2s reads).
  }
}

extern "C" void kernel_launch(void* const* d_in, const int* in_sizes, int n_in,
                              void* d_out, int out_size, void* d_ws, size_t ws_size,
                              hipStream_t stream) {
  const int*   t1   = (const int*)d_in[0];
  const int*   t2   = (const int*)d_in[1];
  const float* numf = (const float*)d_in[2];
  const float* tab1 = (const float*)d_in[3];
  const float* tab2 = (const float*)d_in[4];
  const float* W1   = (const float*)d_in[5];
  const float* b1   = (const float*)d_in[6];
  const float* W2   = (const float*)d_in[7];
  const float* b2   = (const float*)d_in[8];
  float* out = (float*)d_out;
  const int N = in_sizes[0];
  short* Bpack = (short*)d_ws;   // 32 KB

  hipLaunchKernelGGL(prep_kernel, dim3(32), dim3(64), 0, stream, W1, b1, Bpack);
  int ntiles = (N + BM - 1) / BM;
  hipLaunchKernelGGL(fused_kernel, dim3(GRID), dim3(256), 0, stream,
                     t1, t2, numf, tab1, tab2, Bpack, W2, b2, out, N, ntiles);
}